// Round 2
// baseline (586.450 us; speedup 1.0000x reference)
//
#include <hip/hip_runtime.h>

#define IN_C   16
#define OUT_C  16
#define COEF_M 11
#define PLANE  16384   // 128*128
#define WSIZE  3328    // IN_C*OUT_C*COEF_M + 2*IN_C*OUT_C
#define I0     2816    // IN_C*OUT_C*COEF_M
#define I1     3072    // I0 + IN_C*OUT_C

// v3 = v1 (proven 562 us) + per-block phase rotation of the o/i loops.
// Rationale: all plane bases are 64KB-aligned and all blocks sweep (i,o,m)
// in lockstep, so the instantaneous address set spans only a 64KB window ->
// suspected HBM channel-interleave resonance (period > 64KB). Rotating the
// o-loop start by (blockIdx & 15) spreads concurrent accesses across
// 16 x 704KB (704KB = 11*64KB, odd multiple -> covers all power-of-2
// periods up to 1MB). acc[] stays statically indexed; rotation is applied
// only to wave-uniform pointer math and the LDS-write address.
__global__ __launch_bounds__(256) void kan_kernel(
    const float* __restrict__ x, const float* __restrict__ w,
    float* __restrict__ out)
{
    const int tid = threadIdx.x;
    const int px  = tid & 63;        // pixel within block
    const int g   = tid >> 6;        // i-group 0..3
    const int pixel = blockIdx.x * 64 + px;
    const int b  = pixel >> 14;      // PLANE = 2^14, blocks never straddle b
    const int hw = pixel & (PLANE - 1);

    const int phase_o = blockIdx.x & 15;         // adjacent blocks -> different phase
    const int phase_i = (blockIdx.x >> 4) & 3;

    const float* wb = w + (size_t)b * WSIZE * PLANE + hw;
    const float* xb = x + (size_t)b * IN_C * PLANE + hw;

    float acc[OUT_C];
    #pragma unroll
    for (int o = 0; o < OUT_C; ++o) acc[o] = 0.0f;

    for (int iip = 0; iip < 4; ++iip) {
        const int i = g * 4 + ((iip + phase_i) & 3);
        const float xi = xb[(size_t)i * PLANE];

        // Cox-de Boor, order K=3, uniform knots t_j = -1.75 + 0.25*j, j = 0..14
        float bp[14];
        #pragma unroll
        for (int j = 0; j < 14; ++j) {
            const float tj  = -1.75f + 0.25f * j;
            const float tj1 = tj + 0.25f;
            bp[j] = (xi >= tj && xi < tj1) ? 1.0f : 0.0f;
        }
        #pragma unroll
        for (int p = 1; p <= 3; ++p) {
            const float inv = 1.0f / (0.25f * (float)p);
            #pragma unroll
            for (int j = 0; j < 14 - p; ++j) {
                const float tj    = -1.75f + 0.25f * j;
                const float left  = (xi - tj) * inv;
                const float right = ((tj + 0.25f * (float)(p + 1)) - xi) * inv;
                bp[j] = left * bp[j] + right * bp[j + 1];
            }
        }

        const float sx = xi / (1.0f + __expf(-xi));   // silu

        const float* ci = wb + (size_t)(i * (OUT_C * COEF_M)) * PLANE;
        const float* ui = wb + (size_t)(I0 + i * OUT_C) * PLANE;
        const float* ri = wb + (size_t)(I1 + i * OUT_C) * PLANE;

        #pragma unroll
        for (int op = 0; op < OUT_C; ++op) {
            const int o = (op + phase_o) & 15;       // rotated, wave-uniform
            const float* c = ci + (size_t)(o * COEF_M) * PLANE;
            float sp = 0.0f;
            #pragma unroll
            for (int m = 0; m < COEF_M; ++m)
                sp += c[(size_t)m * PLANE] * bp[m];
            acc[op] += ui[(size_t)o * PLANE] * sp + ri[(size_t)o * PLANE] * sx;
        }
    }

    // reduce partial acc across the 4 i-groups via LDS (stride 17 -> <=2-way bank aliasing)
    __shared__ float red[4 * 64 * 17];
    const int row = (g * 64 + px) * 17;
    #pragma unroll
    for (int op = 0; op < OUT_C; ++op)
        red[row + ((op + phase_o) & 15)] = acc[op];   // un-rotate at LDS write
    __syncthreads();

    const int og = g;   // 0..3, one o-quad per wave -> coalesced stores
    #pragma unroll
    for (int k = 0; k < 4; ++k) {
        const int o = og * 4 + k;
        const float s = red[(0 * 64 + px) * 17 + o]
                      + red[(1 * 64 + px) * 17 + o]
                      + red[(2 * 64 + px) * 17 + o]
                      + red[(3 * 64 + px) * 17 + o];
        out[(size_t)b * (OUT_C * PLANE) + (size_t)o * PLANE + hw] = s;
    }
}

extern "C" void kernel_launch(void* const* d_in, const int* in_sizes, int n_in,
                              void* d_out, int out_size, void* d_ws, size_t ws_size,
                              hipStream_t stream) {
    const float* x = (const float*)d_in[0];   // (2,16,128,128) fp32
    const float* w = (const float*)d_in[1];   // (2,3328,128,128) fp32
    float* out = (float*)d_out;               // (2,16,128,128) fp32

    kan_kernel<<<dim3(512), dim3(256), 0, stream>>>(x, w, out);
}

// Round 3
// 562.547 us; speedup vs baseline: 1.0425x; 1.0425x over previous
//
#include <hip/hip_runtime.h>

#define IN_C   16
#define OUT_C  16
#define COEF_M 11
#define PLANE  16384   // 128*128
#define WSIZE  3328    // IN_C*OUT_C*COEF_M + 2*IN_C*OUT_C
#define I0     2816    // IN_C*OUT_C*COEF_M
#define I1     3072    // I0 + IN_C*OUT_C

// v4: request-cluster contrast. Split OUT_C across blocks (8 groups x 2 o),
// widen blocks to 512-px stripes. Each w-plane is now read as 32 x 2KB
// contiguous clusters instead of 256 x 256B. No LDS reduction needed:
// each thread owns the full i-sum for its 2 pixels x 2 outputs.
// grid = 64 stripes x 8 o-groups = 512 blocks (2/CU), 256 thr (4 waves).
__global__ __launch_bounds__(256) void kan_kernel(
    const float* __restrict__ x, const float* __restrict__ w,
    float* __restrict__ out)
{
    const int tid    = threadIdx.x;
    const int stripe = blockIdx.x & 63;   // 64 stripes of 512 px
    const int og     = blockIdx.x >> 6;   // 8 o-groups of 2
    const int px0    = stripe * 512 + tid * 2;
    const int b      = px0 >> 14;         // stripes never straddle b
    const int hw     = px0 & (PLANE - 1);
    const int o0     = og * 2;

    const float* wb = w + (size_t)b * WSIZE * PLANE + hw;
    const float* xb = x + (size_t)b * IN_C * PLANE + hw;

    float acc0a = 0.f, acc0b = 0.f, acc1a = 0.f, acc1b = 0.f;

    for (int i = 0; i < IN_C; ++i) {
        const float2 x2 = *(const float2*)(xb + (size_t)i * PLANE);

        // Cox-de Boor, order K=3, uniform knots t_j = -1.75 + 0.25*j
        float bpa[14], bpb[14];
        #pragma unroll
        for (int j = 0; j < 14; ++j) {
            const float tj  = -1.75f + 0.25f * j;
            const float tj1 = tj + 0.25f;
            bpa[j] = (x2.x >= tj && x2.x < tj1) ? 1.0f : 0.0f;
            bpb[j] = (x2.y >= tj && x2.y < tj1) ? 1.0f : 0.0f;
        }
        #pragma unroll
        for (int p = 1; p <= 3; ++p) {
            const float inv = 1.0f / (0.25f * (float)p);
            #pragma unroll
            for (int j = 0; j < 14 - p; ++j) {
                const float tj  = -1.75f + 0.25f * j;
                const float tp1 = tj + 0.25f * (float)(p + 1);
                bpa[j] = (x2.x - tj) * inv * bpa[j] + (tp1 - x2.x) * inv * bpa[j + 1];
                bpb[j] = (x2.y - tj) * inv * bpb[j] + (tp1 - x2.y) * inv * bpb[j + 1];
            }
        }

        const float sxa = x2.x / (1.0f + __expf(-x2.x));   // silu
        const float sxb = x2.y / (1.0f + __expf(-x2.y));

        const float* c0 = wb + (size_t)(i * (OUT_C * COEF_M) + o0 * COEF_M) * PLANE;
        const float* c1 = c0 + (size_t)COEF_M * PLANE;
        const float* uu = wb + (size_t)(I0 + i * OUT_C + o0) * PLANE;
        const float* rr = wb + (size_t)(I1 + i * OUT_C + o0) * PLANE;

        float sp0a = 0.f, sp0b = 0.f, sp1a = 0.f, sp1b = 0.f;
        #pragma unroll
        for (int m = 0; m < COEF_M; ++m) {
            const float2 cv0 = *(const float2*)(c0 + (size_t)m * PLANE);
            const float2 cv1 = *(const float2*)(c1 + (size_t)m * PLANE);
            sp0a += cv0.x * bpa[m];  sp0b += cv0.y * bpb[m];
            sp1a += cv1.x * bpa[m];  sp1b += cv1.y * bpb[m];
        }
        const float2 uv0 = *(const float2*)(uu);
        const float2 uv1 = *(const float2*)(uu + PLANE);
        const float2 rv0 = *(const float2*)(rr);
        const float2 rv1 = *(const float2*)(rr + PLANE);

        acc0a += uv0.x * sp0a + rv0.x * sxa;
        acc0b += uv0.y * sp0b + rv0.y * sxb;
        acc1a += uv1.x * sp1a + rv1.x * sxa;
        acc1b += uv1.y * sp1b + rv1.y * sxb;
    }

    float* ob = out + (size_t)b * (OUT_C * PLANE) + hw;
    *(float2*)(ob + (size_t)o0 * PLANE)       = make_float2(acc0a, acc0b);
    *(float2*)(ob + (size_t)(o0 + 1) * PLANE) = make_float2(acc1a, acc1b);
}

extern "C" void kernel_launch(void* const* d_in, const int* in_sizes, int n_in,
                              void* d_out, int out_size, void* d_ws, size_t ws_size,
                              hipStream_t stream) {
    const float* x = (const float*)d_in[0];   // (2,16,128,128) fp32
    const float* w = (const float*)d_in[1];   // (2,3328,128,128) fp32
    float* out = (float*)d_out;               // (2,16,128,128) fp32

    kan_kernel<<<dim3(512), dim3(256), 0, stream>>>(x, w, out);
}